// Round 17
// baseline (302.211 us; speedup 1.0000x reference)
//
#include <hip/hip_runtime.h>
#include <stdint.h>
#include <float.h>

// x[4096,256] f32, keys[65536,256] f32, values[65536,10] f32, k=8 (hardcoded).
#define B_ROWS 4096
#define N_KEYS 65536
#define DDIM 256
#define NCH 10

#define NSPLIT 16
#define SPLIT_KEYS (N_KEYS / NSPLIT)       // 4096
#define ROWS_PER_BLK 128
#define CHUNK_KEYS 64
#define NCHUNK (SPLIT_KEYS / CHUNK_KEYS)   // 64

typedef float f32x4 __attribute__((ext_vector_type(4)));
typedef float f32x16 __attribute__((ext_vector_type(16)));
typedef short bf16x8 __attribute__((ext_vector_type(8)));

static __device__ __forceinline__ unsigned short f2bf(float f) {
  unsigned u = __float_as_uint(f);
  return (unsigned short)((u + 0x7FFFu + ((u >> 16) & 1u)) >> 16);
}
static __device__ __forceinline__ unsigned ford(float f) {
  unsigned u = __float_as_uint(f);
  return u ^ ((unsigned)((int)u >> 31) | 0x80000000u);
}
static __device__ __forceinline__ unsigned long long shfl_xor_u64(unsigned long long v, int m) {
  unsigned lo = __shfl_xor((unsigned)v, m, 64);
  unsigned hi = __shfl_xor((unsigned)(v >> 32), m, 64);
  return ((unsigned long long)hi << 32) | lo;
}
static __device__ __forceinline__ double shfl_xor_f64(double v, int m) {
  return __longlong_as_double((long long)shfl_xor_u64((unsigned long long)__double_as_longlong(v), m));
}
static __device__ __forceinline__ void gl_lds16(const void* g, void* l) {
  __builtin_amdgcn_global_load_lds(
      (const __attribute__((address_space(1))) unsigned int*)g,
      (__attribute__((address_space(3))) unsigned int*)l, 16, 0, 0);
}

// ---------------------------------------------------------------------------
// transpose_keys: bf16-convert + transpose + fused ksq. Output: per 32-key
// record [koct 0..31][key 0..31][16B] (16KB). knn_main A-frag reads for the
// 32x32x16 MFMA (lane: key=lane&31, koct=2s+(lane>>5)) are 512B-contiguous
// per 32-lane half: conflict-free. Staging stays a LINEAR copy.
// ---------------------------------------------------------------------------
__global__ __launch_bounds__(256) void transpose_keys(const float* __restrict__ keys,
                                                      unsigned char* __restrict__ kbf,
                                                      float* __restrict__ ksq) {
  __shared__ __align__(16) unsigned char T[128 * 512];
  const int t = threadIdx.x;
  const int lane = t & 63;
  const float4* src = (const float4*)(keys + (size_t)blockIdx.x * 128 * DDIM);
#pragma unroll
  for (int j = 0; j < 32; ++j) {
    int g = j * 256 + t;
    float4 v = src[g];
    int key = g >> 6;
    int u = lane >> 1, sub = lane & 1;
    unsigned lo = ((unsigned)f2bf(v.y) << 16) | f2bf(v.x);
    unsigned hi2 = ((unsigned)f2bf(v.w) << 16) | f2bf(v.z);
    unsigned long long p = ((unsigned long long)hi2 << 32) | lo;
    *(unsigned long long*)&T[key * 512 + ((u ^ (key & 7)) << 4) + (sub << 3)] = p;
    float ss = v.x * v.x + v.y * v.y + v.z * v.z + v.w * v.w;
#pragma unroll
    for (int off = 32; off; off >>= 1) ss += __shfl_xor(ss, off, 64);
    if (lane == 0) ksq[blockIdx.x * 128 + key] = ss;
  }
  __syncthreads();
  uint4* dst = (uint4*)kbf + (size_t)blockIdx.x * 4096; // 4 records of 1024 units
#pragma unroll
  for (int j = 0; j < 16; ++j) {
    int ou = j * 256 + t;                 // rec(4) x koct(32) x key32(32)
    int rec = ou >> 10, rem = ou & 1023;
    int koct = rem >> 5, key32 = rem & 31;
    int keyl = rec * 32 + key32;
    dst[ou] = *(const uint4*)&T[keyl * 512 + ((koct ^ (keyl & 7)) << 4)];
  }
}

// ---------------------------------------------------------------------------
// knn_main (32x32x16 MFMA, operand-flipped; counted-vmcnt double buffer):
// 512 thr = 8 waves = 4 row-groups (ws, 32 rows) x 2 key-halves (mw, 32
// keys). A = keys (M=32, LDS), B = x rows (N=32, regs, pre-scaled by -2) ->
// C: col = x-row (lane&31), row = key ((reg&3)+8*(reg>>2)+4*(lane>>5)).
// Each lane: ONE x-row, 16 key-scores -> tau gate = 1 register.
// Block: 128 rows x one 4096-key split in 64 chunks of 64 keys (2 x 16KB
// records; wave reads record mw). Double-buffered 2x32KB, ONE raw s_barrier
// per chunk with s_waitcnt vmcnt(4): STAGE(c+1) issued right after the
// barrier stays in flight the whole period (never drains). ksq loaded per
// period (L2-resident) and folded into the MFMA C-init.
// Selection: tau filter + append. Streams per (row,split) = mw(2) x lane-
// half(2) x reg-oct(2) = 8; tau_row = max of the 8 running stream minima
// >= v8(split) (8 distinct elements; pigeonhole as before). Overflow
// (cnt>CAP) -> per-split exact rescan in refine: correctness unconditional.
// ---------------------------------------------------------------------------
__global__ __launch_bounds__(512, 4) void knn_main(
    const float* __restrict__ x,
    const unsigned char* __restrict__ kbf,
    const float* __restrict__ ksqg,
    unsigned int* __restrict__ pools,
    unsigned int* __restrict__ counts,
    int CAP) {
  __shared__ __align__(16) unsigned char tiles[2][32768]; // 64KB double buffer
  __shared__ float tauh[2][4][32];  // [mw][ws][col]; monotone, race-benign
  __shared__ unsigned int rowcnt[128];

  const int t = threadIdx.x;
  const int lane = t & 63;
  const int wv = t >> 6;          // 0..7
  const int mw = wv & 1;          // key half (32 keys)
  const int ws = wv >> 1;         // row group (32 rows)
  const int col = lane & 31;      // this lane's x-row within the group
  const int hi5 = lane >> 5;

  const int split = blockIdx.x & (NSPLIT - 1);
  const int rb = (blockIdx.x >> 4) * ROWS_PER_BLK;
  const int sb = split * SPLIT_KEYS;

  const int xrow = rb + ws * 32 + col;
  const int rl = ws * 32 + col;   // block-local row

  // ---- B fragments: one 32-row set, 16 K-slices, PRE-SCALED by -2 (64 VGPR)
  // slice s: lane holds x[xrow][s*16 + hi5*8 .. +7]
  bf16x8 xb[16];
#pragma unroll
  for (int s = 0; s < 16; ++s) {
    const float* p = x + (size_t)xrow * DDIM + s * 16 + hi5 * 8;
    float4 a = *(const float4*)p, b = *(const float4*)(p + 4);
    union { unsigned short us[8]; bf16x8 v; } u;
    u.us[0]=f2bf(-2.f*a.x); u.us[1]=f2bf(-2.f*a.y); u.us[2]=f2bf(-2.f*a.z); u.us[3]=f2bf(-2.f*a.w);
    u.us[4]=f2bf(-2.f*b.x); u.us[5]=f2bf(-2.f*b.y); u.us[6]=f2bf(-2.f*b.z); u.us[7]=f2bf(-2.f*b.w);
    xb[s] = u.v;
  }

  if (t < 128) rowcnt[t] = 0;

  float sminA = FLT_MAX, sminB = FLT_MAX; // per-lane reg-oct stream minima
  const unsigned char* srcbase = kbf + (size_t)sb * 512; // 512B per key
  const size_t pb = ((size_t)xrow * NSPLIT + split) * (size_t)CAP;

  auto STAGE = [&](int c, int buf) { // linear 32KB, 4 x 16B per thread
    const unsigned char* src = srcbase + ((size_t)c << 15);
#pragma unroll
    for (int i = 0; i < 4; ++i)
      gl_lds16(src + (((i * 512) + t) << 4),
               (unsigned char*)tiles[buf] + ((i * 512 + wv * 64) << 4));
  };

  f32x16 acc;

  auto COMPUTE = [&](int c, int buf) {
    // ksq for this lane's 16 keys (4 x float4; L2-resident, issued first)
    const float* kq = ksqg + sb + c * CHUNK_KEYS + mw * 32 + hi5 * 4;
    float4 q0 = *(const float4*)(kq);
    float4 q1 = *(const float4*)(kq + 8);
    float4 q2 = *(const float4*)(kq + 16);
    float4 q3 = *(const float4*)(kq + 24);
    acc[0]=q0.x; acc[1]=q0.y; acc[2]=q0.z; acc[3]=q0.w;
    acc[4]=q1.x; acc[5]=q1.y; acc[6]=q1.z; acc[7]=q1.w;
    acc[8]=q2.x; acc[9]=q2.y; acc[10]=q2.z; acc[11]=q2.w;
    acc[12]=q3.x; acc[13]=q3.y; acc[14]=q3.z; acc[15]=q3.w;
    const unsigned char* rec = tiles[buf] + mw * 16384 + col * 16;
    __builtin_amdgcn_s_setprio(1);
#pragma unroll
    for (int s = 0; s < 16; ++s) {
      bf16x8 af = *(const bf16x8*)(rec + (2 * s + hi5) * 512);
      acc = __builtin_amdgcn_mfma_f32_32x32x16_bf16(af, xb[s], acc, 0, 0, 0);
    }
    __builtin_amdgcn_s_setprio(0);
  };

  auto SEL = [&](int c, bool append, float tau) {
    float m0 = fminf(fminf(fminf(acc[0], acc[1]), fminf(acc[2], acc[3])),
                     fminf(fminf(acc[4], acc[5]), fminf(acc[6], acc[7])));
    float m1 = fminf(fminf(fminf(acc[8], acc[9]), fminf(acc[10], acc[11])),
                     fminf(fminf(acc[12], acc[13]), fminf(acc[14], acc[15])));
    sminA = fminf(sminA, m0);
    sminB = fminf(sminB, m1);
    if (append && fminf(m0, m1) <= tau) { // rare
      const int kbase = c * CHUNK_KEYS + mw * 32 + 4 * hi5;
#pragma unroll
      for (int r = 0; r < 16; ++r) {
        float sc = acc[r];
        if (sc <= tau) {
          int key = kbase + (r & 3) + 8 * (r >> 2); // 12-bit local idx
          unsigned slot = atomicAdd(&rowcnt[rl], 1u);
          if ((int)slot < CAP)
            pools[pb + slot] = (ford(sc) & 0xFFFFF000u) | (unsigned)key;
        }
      }
    }
  };

  auto PUBLISH = [&]() {
    float l = fmaxf(sminA, sminB);            // max of my 2 oct-minima
    l = fmaxf(l, __shfl_xor(l, 32, 64));      // + lane-half partner -> max of 4
    if (hi5 == 0) tauh[mw][ws][col] = l;
  };
  auto RDTAU = [&]() {
    return fmaxf(tauh[0][ws][col], tauh[1][ws][col]); // max of 8 stream minima
  };

  // ---- prologue: tau from chunks 0 and 32 (minima only)
  STAGE(0, 0);
  STAGE(32, 1);
  __syncthreads();                 // full drain (prologue only)
  COMPUTE(0, 0);  SEL(0, false, 0.f);
  COMPUTE(32, 1); SEL(32, false, 0.f);
  PUBLISH();
  __syncthreads();                 // tauh visible; prologue reads done

  // main loop: chunk 0 still valid in buf 0; STAGE(c+1) in flight across
  // each period; vmcnt(4) at entry = STAGE(c) landed (4 newer kq/SEL ops ok).
#pragma unroll 1
  for (int c = 0; c < NCHUNK; ++c) {
    asm volatile("s_waitcnt vmcnt(4)" ::: "memory");
    __builtin_amdgcn_s_barrier();
    const int cs = (c + 1 < NCHUNK) ? c + 1 : 0; // tail: dummy re-stage
    STAGE(cs, (c + 1) & 1);
    float tau = RDTAU();           // lagged/racy: always a valid upper bound
    COMPUTE(c, c & 1);
    SEL(c, true, tau);
    if (c & 1) PUBLISH();
  }

  __syncthreads();
  if (t < 128) counts[(size_t)(rb + t) * NSPLIT + split] = rowcnt[t];
}

// ---------------------------------------------------------------------------
// knn_refine: per row (1 wave): scan the row's 16 pools (overflowed split ->
// exact fp32 rescan of THAT 4096-key split), tournament top-24 by quantized
// score, fp64-exact recompute, true top-8 (idx tiebreak), average values.
// ---------------------------------------------------------------------------
__global__ __launch_bounds__(64) void knn_refine(
    const float* __restrict__ x,
    const float* __restrict__ keys,
    const float* __restrict__ ksq,
    const float* __restrict__ values,
    const unsigned int* __restrict__ pools,
    const unsigned int* __restrict__ counts,
    int CAP,
    float* __restrict__ out) {
  __shared__ float4 xl[64];
  const int row = blockIdx.x;
  const int lane = threadIdx.x;

  xl[lane] = ((const float4*)(x + (size_t)row * DDIM))[lane];
  __syncthreads();

  unsigned long long h[8];
#pragma unroll
  for (int i = 0; i < 8; ++i) h[i] = ~0ULL;

  auto insert = [&](unsigned long long v) {
    if (v < h[7]) {
#pragma unroll
      for (int j = 7; j >= 1; --j) {
        unsigned long long a = h[j - 1];
        unsigned long long mx = a > v ? a : v;
        h[j] = (v < h[j]) ? mx : h[j];
      }
      h[0] = h[0] < v ? h[0] : v;
    }
  };

  for (int s = 0; s < NSPLIT; ++s) {
    unsigned cnt = counts[(size_t)row * NSPLIT + s];
    if ((int)cnt <= CAP) {
      const unsigned int* pp = pools + ((size_t)row * NSPLIT + s) * (size_t)CAP;
      for (int i = lane; i < (int)cnt; i += 64) {
        unsigned p = pp[i];
        unsigned gk = (unsigned)(s * SPLIT_KEYS) + (p & 0xFFFu);
        insert(((unsigned long long)(p & 0xFFFFF000u) << 16) | gk);
      }
    } else {
      // overflow fallback: exact fp32 rescan of this 4096-key split
      for (int kk = lane; kk < SPLIT_KEYS; kk += 64) {
        int gk = s * SPLIT_KEYS + kk;
        const float4* kr = (const float4*)(keys + (size_t)gk * DDIM);
        float acc = 0.f;
#pragma unroll 8
        for (int d = 0; d < 64; ++d) {
          float4 kv = kr[d], xv = xl[d];
          acc = fmaf(kv.x, xv.x, acc); acc = fmaf(kv.y, xv.y, acc);
          acc = fmaf(kv.z, xv.z, acc); acc = fmaf(kv.w, xv.w, acc);
        }
        float sc = fmaf(-2.0f, acc, ksq[gk]);
        insert(((unsigned long long)(ford(sc) & 0xFFFFF000u) << 16) | (unsigned)gk);
      }
    }
  }

  // ---- tournament: top-24 by quantized score (u64 unique: gk in low 16b)
  int myidx = 0;
#pragma unroll 1
  for (int r = 0; r < 24; ++r) {
    unsigned long long m = h[0];
#pragma unroll
    for (int off = 32; off; off >>= 1) {
      unsigned long long o = shfl_xor_u64(m, off);
      m = o < m ? o : m;
    }
    if (lane == r) myidx = (int)(m & 0xFFFFu);
    if (h[0] == m) {
#pragma unroll
      for (int i = 0; i < 7; ++i) h[i] = h[i + 1];
      h[7] = ~0ULL;
    }
  }

  // ---- exact fp64 distance for my candidate
  double dv = 1e300;
  if (lane < 24) {
    const float4* kr = (const float4*)(keys + (size_t)myidx * DDIM);
    double s = 0.0;
#pragma unroll 8
    for (int d = 0; d < 64; ++d) {
      float4 kv = kr[d], xv = xl[d];
      double d0 = (double)xv.x - (double)kv.x;
      double d1 = (double)xv.y - (double)kv.y;
      double d2 = (double)xv.z - (double)kv.z;
      double d3 = (double)xv.w - (double)kv.w;
      s += d0 * d0 + d1 * d1 + d2 * d2 + d3 * d3;
    }
    dv = s;
  }

  int di = myidx;
  int chosen[8];
#pragma unroll
  for (int r = 0; r < 8; ++r) {
    double m = dv; int mi = di;
#pragma unroll
    for (int off = 32; off; off >>= 1) {
      double om = shfl_xor_f64(m, off);
      int omi = __shfl_xor(mi, off, 64);
      if (om < m || (om == m && omi < mi)) { m = om; mi = omi; }
    }
    chosen[r] = mi;
    if (di == mi && dv < 1e300) dv = 1e300;
  }

  if (lane < NCH) {
    double a = 0.0;
#pragma unroll
    for (int r = 0; r < 8; ++r) a += (double)values[(size_t)chosen[r] * NCH + lane];
    out[row * NCH + lane] = (float)(a * 0.125);
  }
}

// ---------------------------------------------------------------------------
extern "C" void kernel_launch(void* const* d_in, const int* in_sizes, int n_in,
                              void* d_out, int out_size, void* d_ws, size_t ws_size,
                              hipStream_t stream) {
  (void)in_sizes; (void)n_in; (void)out_size;
  const float* x      = (const float*)d_in[0];
  const float* keys   = (const float*)d_in[1];
  const float* values = (const float*)d_in[2];
  float* out = (float*)d_out;

  char* ws = (char*)d_ws;
  unsigned char* kbf = (unsigned char*)ws;                            // 32 MB transposed bf16 keys
  float* ksq   = (float*)(ws + 33554432);                             // 256 KB
  unsigned int* counts = (unsigned int*)(ws + 33554432 + 262144);     // 256 KB (4096x16)
  unsigned int* pools  = (unsigned int*)(ws + 33554432 + 262144 + 262144);

  size_t base = 33554432 + 262144 + 262144;
  size_t cap = (ws_size > base) ? (ws_size - base) / ((size_t)B_ROWS * NSPLIT * 4) : 60;
  if (cap < 60) cap = 60;      // pool ends <49.8 MB (< proven 50.6)
  if (cap > 512) cap = 512;
  int CAP = (int)cap;

  transpose_keys<<<N_KEYS / 128, 256, 0, stream>>>(keys, kbf, ksq);
  knn_main<<<(B_ROWS / ROWS_PER_BLK) * NSPLIT, 512, 0, stream>>>(
      x, kbf, ksq, pools, counts, CAP);
  knn_refine<<<B_ROWS, 64, 0, stream>>>(x, keys, ksq, values, pools, counts, CAP, out);
}